// Round 15
// baseline (3016.995 us; speedup 1.0000x reference)
//
#include <hip/hip_runtime.h>
#include <float.h>

#define TT 4096
#define BB 4
#define CC 512
#define DD 256
#define KK 2048
#define MM (BB*TT)        // 16384 rows (b,t)
#define NBOOKS 22
#define EPS_PAIR 0.5f
#define EPS_FULL 0.5f
#define ZSTR 260          // 260 % 32 == 4 -> conflict-light
#define RPB 16            // rows per block (small -> high occupancy)

typedef _Float16 half8_t __attribute__((ext_vector_type(8)));
typedef float f32x4 __attribute__((ext_vector_type(4)));

// ---- packed-u32 top-3 tracking ----
// key = monotone(float) with low 11 bits replaced by code index.
// min over packed keys == (score, code) lexicographic min (score truncated
// to 21-bit key; trunc err <= 0.25 for |s|<1024, covered by EPS + fp64 refine).
__device__ __forceinline__ uint32_t packsc(float s, int code) {
  uint32_t b = __float_as_uint(s);
  uint32_t key = b ^ ((uint32_t)((int32_t)b >> 31) | 0x80000000u);
  return (key & 0xFFFFF800u) | (uint32_t)code;
}
__device__ __forceinline__ float unpacksc(uint32_t p) {
  uint32_t key = p & 0xFFFFF800u;
  uint32_t b = (key & 0x80000000u) ? (key ^ 0x80000000u) : ~key;
  return __uint_as_float(b);
}
// branchless insert into sorted triple (5 min/max ops)
__device__ __forceinline__ void ins3(uint32_t& v1, uint32_t& v2, uint32_t& v3,
                                     uint32_t p) {
  uint32_t t1 = max(v1, p); v1 = min(v1, p);
  uint32_t t2 = max(v2, t1); v2 = min(v2, t1);
  v3 = min(v3, t2);
}

// ---------------- projection: xs = Win_s @ x, xa = Win_a @ x ----------------
__global__ __launch_bounds__(256) void proj_kernel(const float* __restrict__ x,
    const float* __restrict__ Ws, const float* __restrict__ Wa,
    float* __restrict__ xs, float* __restrict__ xa)
{
  __shared__ float xt[16*64];
  __shared__ float wsl[16*68];
  __shared__ float wal[16*68];
  const int tid = threadIdx.x;
  const int t0 = blockIdx.x*64, d0 = blockIdx.y*64, b = blockIdx.z;
  const int u = tid & 63, cq = tid >> 6;
  const int tx = tid & 15, ty = tid >> 4;
  const float* xb = x + (size_t)b*CC*TT;
  float accS[4][4] = {{0}}, accA[4][4] = {{0}};
  for (int c0 = 0; c0 < CC; c0 += 16) {
    __syncthreads();
    #pragma unroll
    for (int i = 0; i < 4; ++i) {
      int cc = cq*4 + i;
      xt[cc*64 + u] = xb[(size_t)(c0+cc)*TT + t0 + u];
    }
    {
      float4 wv = *(const float4*)&Ws[(size_t)(d0+u)*CC + c0 + cq*4];
      wsl[(cq*4+0)*68 + u] = wv.x; wsl[(cq*4+1)*68 + u] = wv.y;
      wsl[(cq*4+2)*68 + u] = wv.z; wsl[(cq*4+3)*68 + u] = wv.w;
      wv = *(const float4*)&Wa[(size_t)(d0+u)*CC + c0 + cq*4];
      wal[(cq*4+0)*68 + u] = wv.x; wal[(cq*4+1)*68 + u] = wv.y;
      wal[(cq*4+2)*68 + u] = wv.z; wal[(cq*4+3)*68 + u] = wv.w;
    }
    __syncthreads();
    #pragma unroll
    for (int cc = 0; cc < 16; ++cc) {
      float4 tq = *(const float4*)&xt[cc*64 + ty*4];
      float4 sq = *(const float4*)&wsl[cc*68 + tx*4];
      float4 aq = *(const float4*)&wal[cc*68 + tx*4];
      float tf[4] = {tq.x,tq.y,tq.z,tq.w};
      float sf[4] = {sq.x,sq.y,sq.z,sq.w};
      float af[4] = {aq.x,aq.y,aq.z,aq.w};
      #pragma unroll
      for (int i = 0; i < 4; ++i)
        #pragma unroll
        for (int j = 0; j < 4; ++j) {
          accS[i][j] = fmaf(tf[i], sf[j], accS[i][j]);
          accA[i][j] = fmaf(tf[i], af[j], accA[i][j]);
        }
    }
  }
  #pragma unroll
  for (int i = 0; i < 4; ++i) {
    size_t r = (size_t)b*TT + t0 + ty*4 + i;
    float4 o;
    o.x = accS[i][0]; o.y = accS[i][1]; o.z = accS[i][2]; o.w = accS[i][3];
    *(float4*)&xs[r*DD + d0 + tx*4] = o;
    o.x = accA[i][0]; o.y = accA[i][1]; o.z = accA[i][2]; o.w = accA[i][3];
    *(float4*)&xa[r*DD + d0 + tx*4] = o;
  }
}

// ---------------- e2[k] = sum_d E[k][d]^2 ----------------
__global__ __launch_bounds__(256) void e2_kernel(const float* __restrict__ E,
    float* __restrict__ e2)
{
  int gid = blockIdx.x*256 + threadIdx.x;
  int wid = gid >> 6, lane = gid & 63;
  if (wid < 18*KK) {
    float4 v = *(const float4*)&E[(size_t)wid*DD + lane*4];
    float s = v.x*v.x + v.y*v.y + v.z*v.z + v.w*v.w;
    #pragma unroll
    for (int m = 1; m <= 32; m <<= 1) s += __shfl_xor(s, m);
    if (lane == 0) e2[wid] = s;
  }
}

// ---------------- convert E -> f16 plane ----------------
__global__ __launch_bounds__(256) void cvt_e16_kernel(const float* __restrict__ E,
    _Float16* __restrict__ E16)
{
  size_t i = ((size_t)blockIdx.x*256 + threadIdx.x)*8;
  float4 u = *(const float4*)&E[i];
  float4 v = *(const float4*)&E[i+4];
  half8_t h;
  h[0]=(_Float16)u.x; h[1]=(_Float16)u.y; h[2]=(_Float16)u.z; h[3]=(_Float16)u.w;
  h[4]=(_Float16)v.x; h[5]=(_Float16)v.y; h[6]=(_Float16)v.z; h[7]=(_Float16)v.w;
  *(half8_t*)&E16[i] = h;
}

// ---------------- FUSED encode: all 22 books, one kernel ----------------
// 1024 blocks x 16 rows, 256 threads = 4 waves. Per wave: A[8] (16 rows,
// full K, 32 VGPR) x 512-code quarter. Working set ~95 VGPR + ~26KB LDS
// -> 4-5 blocks/CU = 4-5 waves/SIMD of TLP (the round-14 shape was stuck
// at 2). Two independent 4-deep MFMA chains per nt. Packed-u32 top-3;
// fp64 pairwise/full refine for near-ties.
__global__ __launch_bounds__(256)
void fused_encode_kernel(
    const float* __restrict__ xs_g, const float* __restrict__ xa_g,
    const float* __restrict__ E, const _Float16* __restrict__ E16,
    const float* __restrict__ e2, int* __restrict__ codes0,
    float* __restrict__ codes_f, float* __restrict__ aco_g)
{
  const int tid = threadIdx.x;
  const int lane = tid & 63, wave = tid >> 6;   // 4 waves
  const int ln15 = lane & 15, lq = lane >> 4;   // lq 0..3
  const int row0 = blockIdx.x * RPB;

  __shared__ float Z[RPB][ZSTR];                // residual panel (~16.6KB)
  __shared__ float e2s[KK];                     // e2 for this book (8KB)
  __shared__ uint32_t L1[4][RPB], L2[4][RPB], L3[4][RPB];
  __shared__ int   codes_s[RPB];
  __shared__ int   flist[RPB], plist[RPB];
  __shared__ int   nfull, npair;
  __shared__ double Rv[4];
  __shared__ int    Ri[4];

  const int ldr = tid >> 4, cg = tid & 15;      // panel-load / aco: row, col-grp
  const int sr = tid >> 4, sg = tid & 15;       // subtract: 16 thr/row

  for (int ib = 0; ib < NBOOKS; ++ib) {
    const int book = (ib <= 17) ? ib : 17;
    const float*     Eb   = E   + (size_t)book*KK*DD;
    const _Float16*  E16b = E16 + (size_t)book*KK*DD;
    const float*     e2b  = e2  + (size_t)book*KK;

    if (ib <= 1) {                              // ib0: xs panel; ib1: xa panel
      const float* src = (ib == 0) ? xs_g : xa_g;
      const float* sp = src + (size_t)(row0 + ldr)*DD;
      #pragma unroll
      for (int j = 0; j < 4; ++j)
        *(float4*)&Z[ldr][cg*4 + j*64] = *(const float4*)(sp + cg*4 + j*64);
    }
    // stage e2 for this book into LDS (256 threads x 8 floats)
    {
      *(float4*)&e2s[tid*8]     = *(const float4*)&e2b[tid*8];
      *(float4*)&e2s[tid*8 + 4] = *(const float4*)&e2b[tid*8 + 4];
    }
    if (tid == 0) { nfull = 0; npair = 0; }
    __syncthreads();                            // S1

    // ---- A fragments from LDS (f32 -> f16): 16 rows, full K ----
    half8_t A[8];
    #pragma unroll
    for (int ks = 0; ks < 8; ++ks) {
      const float* zp = &Z[ln15][lq*8 + ks*32];
      float4 u = *(const float4*)zp;
      float4 v = *(const float4*)(zp + 4);
      half8_t a;
      a[0]=(_Float16)u.x; a[1]=(_Float16)u.y; a[2]=(_Float16)u.z; a[3]=(_Float16)u.w;
      a[4]=(_Float16)v.x; a[5]=(_Float16)v.y; a[6]=(_Float16)v.z; a[7]=(_Float16)v.w;
      A[ks] = a;
    }

    uint32_t p1[4], p2[4], p3[4];
    #pragma unroll
    for (int j = 0; j < 4; ++j) {
      p1[j] = 0xFFFFFFFFu; p2[j] = 0xFFFFFFFFu; p3[j] = 0xFFFFFFFFu;
    }

    const _Float16* ebase = E16b + (size_t)(wave*512 + ln15)*DD + lq*8;

    for (int nt = 0; nt < 32; ++nt) {
      const _Float16* bp = ebase + (size_t)nt*16*DD;
      int code = wave*512 + nt*16 + ln15;
      float e2v = e2s[code];
      f32x4 aL = (f32x4){0.f,0.f,0.f,0.f};
      f32x4 aH = (f32x4){0.f,0.f,0.f,0.f};
      // two independent 4-deep chains
      {
        half8_t B0 = *(const half8_t*)(bp + 0*32);
        half8_t B1 = *(const half8_t*)(bp + 1*32);
        half8_t B2 = *(const half8_t*)(bp + 2*32);
        half8_t B3 = *(const half8_t*)(bp + 3*32);
        aL = __builtin_amdgcn_mfma_f32_16x16x32_f16(A[0], B0, aL, 0, 0, 0);
        aL = __builtin_amdgcn_mfma_f32_16x16x32_f16(A[1], B1, aL, 0, 0, 0);
        aL = __builtin_amdgcn_mfma_f32_16x16x32_f16(A[2], B2, aL, 0, 0, 0);
        aL = __builtin_amdgcn_mfma_f32_16x16x32_f16(A[3], B3, aL, 0, 0, 0);
      }
      {
        half8_t B4 = *(const half8_t*)(bp + 4*32);
        half8_t B5 = *(const half8_t*)(bp + 5*32);
        half8_t B6 = *(const half8_t*)(bp + 6*32);
        half8_t B7 = *(const half8_t*)(bp + 7*32);
        aH = __builtin_amdgcn_mfma_f32_16x16x32_f16(A[4], B4, aH, 0, 0, 0);
        aH = __builtin_amdgcn_mfma_f32_16x16x32_f16(A[5], B5, aH, 0, 0, 0);
        aH = __builtin_amdgcn_mfma_f32_16x16x32_f16(A[6], B6, aH, 0, 0, 0);
        aH = __builtin_amdgcn_mfma_f32_16x16x32_f16(A[7], B7, aH, 0, 0, 0);
      }
      // scores + packed top-3. C/D: col(code)=lane&15, row=(lane>>4)*4+reg
      #pragma unroll
      for (int j = 0; j < 4; ++j) {
        float u = fmaf(-2.f, aL[j] + aH[j], e2v);
        ins3(p1[j], p2[j], p3[j], packsc(u, code));
      }
    }

    // ---- in-wave reduce over the 16 code-columns, then cross-wave ----
    #pragma unroll
    for (int j = 0; j < 4; ++j) {
      uint32_t v1 = p1[j], v2 = p2[j], v3 = p3[j];
      #pragma unroll
      for (int m = 1; m <= 8; m <<= 1) {
        uint32_t w1 = (uint32_t)__shfl_xor((int)v1, m);
        uint32_t w2 = (uint32_t)__shfl_xor((int)v2, m);
        uint32_t w3 = (uint32_t)__shfl_xor((int)v3, m);
        ins3(v1, v2, v3, w1);
        ins3(v1, v2, v3, w2);
        ins3(v1, v2, v3, w3);
      }
      if (ln15 == 0) {
        int rl = lq*4 + j;                      // 16 rows
        L1[wave][rl] = v1; L2[wave][rl] = v2; L3[wave][rl] = v3;
      }
    }
    __syncthreads();                            // S2
    if (tid < RPB) {
      uint32_t v1 = L1[0][tid], v2 = L2[0][tid], v3 = L3[0][tid];
      #pragma unroll
      for (int w = 1; w < 4; ++w) {
        ins3(v1, v2, v3, L1[w][tid]);
        ins3(v1, v2, v3, L2[w][tid]);
        ins3(v1, v2, v3, L3[w][tid]);
      }
      int a1 = (int)(v1 & 2047u), a2 = (int)(v2 & 2047u);
      float f1 = unpacksc(v1), f2 = unpacksc(v2), f3 = unpacksc(v3);
      codes_s[tid] = a1;
      int rg = row0 + tid;
      codes_f[((size_t)(rg >> 12)*NBOOKS + ib)*TT + (rg & (TT-1))] = (float)a1;
      if (ib == 0) codes0[rg] = a1;
      if (f3 - f1 < EPS_FULL) {
        flist[atomicAdd(&nfull, 1)] = tid;
      } else if (f2 - f1 < EPS_PAIR) {
        plist[atomicAdd(&npair, 1)] = tid | (a1 << 6) | (a2 << 17);
      }
    }
    __syncthreads();                            // S3

    // ---- full fp64 re-rank (rare: 3rd-best within EPS of best) ----
    int nfl = nfull;
    for (int f = 0; f < nfl; ++f) {
      int row = flist[f];
      double bestv = DBL_MAX; int besti = 0x7fffffff;
      #pragma unroll
      for (int q = 0; q < 8; ++q) {
        int k = q*256 + tid;
        const float* er = Eb + (size_t)k*DD;
        double s = 0.0;
        for (int d = 0; d < DD; d += 4) {
          float4 e = *(const float4*)(er + d);
          double d0 = (double)Z[row][d+0] - (double)e.x; s += d0*d0;
          double d1 = (double)Z[row][d+1] - (double)e.y; s += d1*d1;
          double d2 = (double)Z[row][d+2] - (double)e.z; s += d2*d2;
          double d3 = (double)Z[row][d+3] - (double)e.w; s += d3*d3;
        }
        if (s < bestv || (s == bestv && k < besti)) { bestv = s; besti = k; }
      }
      #pragma unroll
      for (int m = 1; m <= 32; m <<= 1) {
        double ov = __shfl_xor(bestv, m);
        int    oi = __shfl_xor(besti, m);
        if (ov < bestv || (ov == bestv && oi < besti)) { bestv = ov; besti = oi; }
      }
      if (lane == 0) { Rv[wave] = bestv; Ri[wave] = besti; }
      __syncthreads();
      if (tid == 0) {
        double bvv = Rv[0]; int bii = Ri[0];
        #pragma unroll
        for (int w = 1; w < 4; ++w)
          if (Rv[w] < bvv || (Rv[w] == bvv && Ri[w] < bii)) { bvv = Rv[w]; bii = Ri[w]; }
        codes_s[row] = bii;
        int rg = row0 + row;
        codes_f[((size_t)(rg >> 12)*NBOOKS + ib)*TT + (rg & (TT-1))] = (float)bii;
        if (ib == 0) codes0[rg] = bii;
      }
      __syncthreads();
    }

    // ---- pairwise fp64 refine: one wave per flagged row, compares top-2 ----
    {
      int npr = npair;
      for (int f = wave; f < npr; f += 4) {
        int pk = plist[f];
        int row = pk & 63;
        int c1 = (pk >> 6) & 2047, c2 = (pk >> 17) & 2047;
        int cc = (lane < 32) ? c1 : c2;
        const float* er = Eb + (size_t)cc*DD + (lane & 31)*8;
        const float* zr = &Z[row][(lane & 31)*8];
        double s = 0.0;
        #pragma unroll
        for (int d = 0; d < 8; ++d) {
          double df = (double)zr[d] - (double)er[d];
          s += df*df;
        }
        #pragma unroll
        for (int m = 1; m <= 16; m <<= 1) s += __shfl_xor(s, m);
        double so = __shfl_xor(s, 32);
        double d1 = (lane < 32) ? s : so;
        double d2 = (lane < 32) ? so : s;
        int win = (d2 < d1 || (d2 == d1 && c2 < c1)) ? c2 : c1;
        if (lane == 0) {
          codes_s[row] = win;
          int rg = row0 + row;
          codes_f[((size_t)(rg >> 12)*NBOOKS + ib)*TT + (rg & (TT-1))] = (float)win;
          if (ib == 0) codes0[rg] = win;
        }
      }
    }
    __syncthreads();                            // S4: codes_s final

    // ---- f32 residual subtract in LDS (acoustic books only) ----
    if (ib >= 1) {
      int code = codes_s[sr];
      const float* er = Eb + (size_t)code*DD;
      #pragma unroll
      for (int j = 0; j < 4; ++j) {
        int c = sg*4 + j*64;
        float4 e = *(const float4*)(er + c);
        float4 z = *(const float4*)&Z[sr][c];
        z.x -= e.x; z.y -= e.y; z.z -= e.z; z.w -= e.w;
        *(float4*)&Z[sr][c] = z;
      }
    }
    __syncthreads();                            // S5: Z stable for next book
  }

  // ---- aco = xa_initial - xa_final ----
  {
    const float* xp = xa_g + (size_t)(row0 + ldr)*DD;
    float*       ap = aco_g + (size_t)(row0 + ldr)*DD;
    #pragma unroll
    for (int j = 0; j < 4; ++j) {
      int c = cg*4 + j*64;
      float4 x0 = *(const float4*)(xp + c);
      float4 zf = *(const float4*)&Z[ldr][c];
      float4 o;
      o.x = x0.x - zf.x; o.y = x0.y - zf.y; o.z = x0.z - zf.z; o.w = x0.w - zf.w;
      *(float4*)(ap + c) = o;
    }
  }
}

// ---------------- decode ----------------
__global__ __launch_bounds__(256) void final_kernel(
    const float* __restrict__ Wos, const float* __restrict__ Woa,
    const float* __restrict__ E0, const int* __restrict__ codes0,
    const float* __restrict__ aco, float* __restrict__ out)
{
  __shared__ float wsl[16*68], wal[16*68], sml[16*68], acl[16*68];
  const int tid = threadIdx.x;
  const int t0 = blockIdx.x*64, c0 = blockIdx.y*64, b = blockIdx.z;
  const int u = tid & 63, dq = tid >> 6;
  const int tx = tid & 15, ty = tid >> 4;
  int code = codes0[b*TT + t0 + u];
  const float* smr = E0 + (size_t)code*DD;
  const float* acr = aco + (size_t)(b*TT + t0 + u)*DD;
  const float* wsr = Wos + (size_t)(c0+u)*DD;
  const float* war = Woa + (size_t)(c0+u)*DD;
  float accS[4][4] = {{0}}, accA[4][4] = {{0}};
  for (int dc0 = 0; dc0 < DD; dc0 += 16) {
    __syncthreads();
    float4 v;
    v = *(const float4*)(wsr + dc0 + dq*4);
    wsl[(dq*4+0)*68+u]=v.x; wsl[(dq*4+1)*68+u]=v.y; wsl[(dq*4+2)*68+u]=v.z; wsl[(dq*4+3)*68+u]=v.w;
    v = *(const float4*)(war + dc0 + dq*4);
    wal[(dq*4+0)*68+u]=v.x; wal[(dq*4+1)*68+u]=v.y; wal[(dq*4+2)*68+u]=v.z; wal[(dq*4+3)*68+u]=v.w;
    v = *(const float4*)(smr + dc0 + dq*4);
    sml[(dq*4+0)*68+u]=v.x; sml[(dq*4+1)*68+u]=v.y; sml[(dq*4+2)*68+u]=v.z; sml[(dq*4+3)*68+u]=v.w;
    v = *(const float4*)(acr + dc0 + dq*4);
    acl[(dq*4+0)*68+u]=v.x; acl[(dq*4+1)*68+u]=v.y; acl[(dq*4+2)*68+u]=v.z; acl[(dq*4+3)*68+u]=v.w;
    __syncthreads();
    #pragma unroll
    for (int d = 0; d < 16; ++d) {
      float4 cs = *(const float4*)&wsl[d*68 + tx*4];
      float4 ca = *(const float4*)&wal[d*68 + tx*4];
      float4 ts = *(const float4*)&sml[d*68 + ty*4];
      float4 ta = *(const float4*)&acl[d*68 + ty*4];
      float csf[4]={cs.x,cs.y,cs.z,cs.w}, caf[4]={ca.x,ca.y,ca.z,ca.w};
      float tsf[4]={ts.x,ts.y,ts.z,ts.w}, taf[4]={ta.x,ta.y,ta.z,ta.w};
      #pragma unroll
      for (int i = 0; i < 4; ++i)
        #pragma unroll
        for (int j = 0; j < 4; ++j) {
          accS[i][j] = fmaf(csf[i], tsf[j], accS[i][j]);
          accA[i][j] = fmaf(caf[i], taf[j], accA[i][j]);
        }
    }
  }
  size_t ob = (size_t)b*CC*TT;
  #pragma unroll
  for (int i = 0; i < 4; ++i) {
    float4 r;
    r.x = accS[i][0] + accA[i][0];
    r.y = accS[i][1] + accA[i][1];
    r.z = accS[i][2] + accA[i][2];
    r.w = accS[i][3] + accA[i][3];
    *(float4*)&out[ob + (size_t)(c0 + tx*4 + i)*TT + t0 + ty*4] = r;
  }
}

extern "C" void kernel_launch(void* const* d_in, const int* in_sizes, int n_in,
                              void* d_out, int out_size, void* d_ws, size_t ws_size,
                              hipStream_t stream) {
  const float* x    = (const float*)d_in[0];
  const float* Wins = (const float*)d_in[1];
  const float* Wina = (const float*)d_in[2];
  const float* Wos  = (const float*)d_in[3];
  const float* Woa  = (const float*)d_in[4];
  const float* E    = (const float*)d_in[5];
  float* out = (float*)d_out;
  float* codes_f = out + (size_t)BB*CC*TT;

  // E16 plane lives in the front of d_out (18.9MB; codes_f starts at 33.6MB;
  // out[0:8.4M floats] fully overwritten by final_kernel afterwards).
  _Float16* E16 = (_Float16*)d_out;

  float* xs  = (float*)d_ws;
  float* xa  = xs + (size_t)MM*DD;
  float* aco = xa + (size_t)MM*DD;
  float* e2  = aco + (size_t)MM*DD;
  int* codes_i = (int*)(e2 + 18*KK);

  proj_kernel<<<dim3(TT/64, DD/64, BB), 256, 0, stream>>>(x, Wins, Wina, xs, xa);
  e2_kernel<<<(18*KK*64)/256, 256, 0, stream>>>(E, e2);
  cvt_e16_kernel<<<(18*KK*DD)/8/256, 256, 0, stream>>>(E, E16);

  fused_encode_kernel<<<MM/RPB, 256, 0, stream>>>(xs, xa, E, E16, e2,
                                                  codes_i, codes_f, aco);

  final_kernel<<<dim3(TT/64, CC/64, BB), 256, 0, stream>>>(Wos, Woa, E, codes_i, aco, out);
}

// Round 16
// 2238.353 us; speedup vs baseline: 1.3479x; 1.3479x over previous
//
#include <hip/hip_runtime.h>
#include <float.h>

#define TT 4096
#define BB 4
#define CC 512
#define DD 256
#define KK 2048
#define MM (BB*TT)        // 16384 rows (b,t)
#define NBOOKS 22
#define EPS_PAIR 0.4f
#define EPS_FULL 0.4f
#define SHIFT 256.0f      // argmin-invariant score shift (shrinks packed-key trunc)
#define ZSTR 260          // 260 % 32 == 4 -> conflict-light
#define RPB 32            // rows per block

typedef _Float16 half8_t __attribute__((ext_vector_type(8)));
typedef float f32x4 __attribute__((ext_vector_type(4)));

// ---- packed-u32 top-3 tracking ----
// key = monotone(float) with low 11 bits replaced by code index.
__device__ __forceinline__ uint32_t packsc(float s, int code) {
  uint32_t b = __float_as_uint(s);
  uint32_t key = b ^ ((uint32_t)((int32_t)b >> 31) | 0x80000000u);
  return (key & 0xFFFFF800u) | (uint32_t)code;
}
__device__ __forceinline__ float unpacksc(uint32_t p) {
  uint32_t key = p & 0xFFFFF800u;
  uint32_t b = (key & 0x80000000u) ? (key ^ 0x80000000u) : ~key;
  return __uint_as_float(b);
}
// branchless insert into sorted triple (5 min/max ops)
__device__ __forceinline__ void ins3(uint32_t& v1, uint32_t& v2, uint32_t& v3,
                                     uint32_t p) {
  uint32_t t1 = max(v1, p); v1 = min(v1, p);
  uint32_t t2 = max(v2, t1); v2 = min(v2, t1);
  v3 = min(v3, t2);
}

// ---------------- projection: xs = Win_s @ x, xa = Win_a @ x ----------------
__global__ __launch_bounds__(256) void proj_kernel(const float* __restrict__ x,
    const float* __restrict__ Ws, const float* __restrict__ Wa,
    float* __restrict__ xs, float* __restrict__ xa)
{
  __shared__ float xt[16*64];
  __shared__ float wsl[16*68];
  __shared__ float wal[16*68];
  const int tid = threadIdx.x;
  const int t0 = blockIdx.x*64, d0 = blockIdx.y*64, b = blockIdx.z;
  const int u = tid & 63, cq = tid >> 6;
  const int tx = tid & 15, ty = tid >> 4;
  const float* xb = x + (size_t)b*CC*TT;
  float accS[4][4] = {{0}}, accA[4][4] = {{0}};
  for (int c0 = 0; c0 < CC; c0 += 16) {
    __syncthreads();
    #pragma unroll
    for (int i = 0; i < 4; ++i) {
      int cc = cq*4 + i;
      xt[cc*64 + u] = xb[(size_t)(c0+cc)*TT + t0 + u];
    }
    {
      float4 wv = *(const float4*)&Ws[(size_t)(d0+u)*CC + c0 + cq*4];
      wsl[(cq*4+0)*68 + u] = wv.x; wsl[(cq*4+1)*68 + u] = wv.y;
      wsl[(cq*4+2)*68 + u] = wv.z; wsl[(cq*4+3)*68 + u] = wv.w;
      wv = *(const float4*)&Wa[(size_t)(d0+u)*CC + c0 + cq*4];
      wal[(cq*4+0)*68 + u] = wv.x; wal[(cq*4+1)*68 + u] = wv.y;
      wal[(cq*4+2)*68 + u] = wv.z; wal[(cq*4+3)*68 + u] = wv.w;
    }
    __syncthreads();
    #pragma unroll
    for (int cc = 0; cc < 16; ++cc) {
      float4 tq = *(const float4*)&xt[cc*64 + ty*4];
      float4 sq = *(const float4*)&wsl[cc*68 + tx*4];
      float4 aq = *(const float4*)&wal[cc*68 + tx*4];
      float tf[4] = {tq.x,tq.y,tq.z,tq.w};
      float sf[4] = {sq.x,sq.y,sq.z,sq.w};
      float af[4] = {aq.x,aq.y,aq.z,aq.w};
      #pragma unroll
      for (int i = 0; i < 4; ++i)
        #pragma unroll
        for (int j = 0; j < 4; ++j) {
          accS[i][j] = fmaf(tf[i], sf[j], accS[i][j]);
          accA[i][j] = fmaf(tf[i], af[j], accA[i][j]);
        }
    }
  }
  #pragma unroll
  for (int i = 0; i < 4; ++i) {
    size_t r = (size_t)b*TT + t0 + ty*4 + i;
    float4 o;
    o.x = accS[i][0]; o.y = accS[i][1]; o.z = accS[i][2]; o.w = accS[i][3];
    *(float4*)&xs[r*DD + d0 + tx*4] = o;
    o.x = accA[i][0]; o.y = accA[i][1]; o.z = accA[i][2]; o.w = accA[i][3];
    *(float4*)&xa[r*DD + d0 + tx*4] = o;
  }
}

// ---------------- e2[k] = sum_d E[k][d]^2 ----------------
__global__ __launch_bounds__(256) void e2_kernel(const float* __restrict__ E,
    float* __restrict__ e2)
{
  int gid = blockIdx.x*256 + threadIdx.x;
  int wid = gid >> 6, lane = gid & 63;
  if (wid < 18*KK) {
    float4 v = *(const float4*)&E[(size_t)wid*DD + lane*4];
    float s = v.x*v.x + v.y*v.y + v.z*v.z + v.w*v.w;
    #pragma unroll
    for (int m = 1; m <= 32; m <<= 1) s += __shfl_xor(s, m);
    if (lane == 0) e2[wid] = s;
  }
}

// ---------------- convert E -> f16 plane ----------------
__global__ __launch_bounds__(256) void cvt_e16_kernel(const float* __restrict__ E,
    _Float16* __restrict__ E16)
{
  size_t i = ((size_t)blockIdx.x*256 + threadIdx.x)*8;
  float4 u = *(const float4*)&E[i];
  float4 v = *(const float4*)&E[i+4];
  half8_t h;
  h[0]=(_Float16)u.x; h[1]=(_Float16)u.y; h[2]=(_Float16)u.z; h[3]=(_Float16)u.w;
  h[4]=(_Float16)v.x; h[5]=(_Float16)v.y; h[6]=(_Float16)v.z; h[7]=(_Float16)v.w;
  *(half8_t*)&E16[i] = h;
}

// ---------------- FUSED encode: all 22 books, one kernel ----------------
// 512 blocks x 32 rows, 512 threads = 8 waves => 16 waves/CU (4/SIMD), 2x
// the 4-wave shape's TLP at identical traffic. Per wave: A[2][8] (32 rows,
// 64 VGPR) x 256-code eighth; working set ~122 <= the 128-cap for 8-wave
// blocks -> no spill. Packed-u32 top-3 (score shifted by -256 to shrink
// key truncation); fp64 pairwise/full refine for near-ties.
__global__ __launch_bounds__(512)
void fused_encode_kernel(
    const float* __restrict__ xs_g, const float* __restrict__ xa_g,
    const float* __restrict__ E, const _Float16* __restrict__ E16,
    const float* __restrict__ e2, int* __restrict__ codes0,
    float* __restrict__ codes_f, float* __restrict__ aco_g)
{
  const int tid = threadIdx.x;
  const int lane = tid & 63, wave = tid >> 6;   // 8 waves
  const int ln15 = lane & 15, lq = lane >> 4;   // lq 0..3
  const int row0 = blockIdx.x * RPB;

  __shared__ float Z[RPB][ZSTR];                // residual panel (~33KB)
  __shared__ float e2s[KK];                     // e2 for this book (8KB)
  __shared__ uint32_t L1[8][RPB], L2[8][RPB], L3[8][RPB];
  __shared__ int   codes_s[RPB];
  __shared__ int   flist[RPB], plist[RPB];
  __shared__ int   nfull, npair;
  __shared__ double Rv[8];
  __shared__ int    Ri[8];

  const int ldr = tid >> 4, cg = tid & 15;      // panel-load/subtract/aco: 16 thr/row
  const int sr = ldr, sg = cg;

  for (int ib = 0; ib < NBOOKS; ++ib) {
    const int book = (ib <= 17) ? ib : 17;
    const float*     Eb   = E   + (size_t)book*KK*DD;
    const _Float16*  E16b = E16 + (size_t)book*KK*DD;
    const float*     e2b  = e2  + (size_t)book*KK;

    if (ib <= 1) {                              // ib0: xs panel; ib1: xa panel
      const float* src = (ib == 0) ? xs_g : xa_g;
      const float* sp = src + (size_t)(row0 + ldr)*DD;
      #pragma unroll
      for (int j = 0; j < 4; ++j)
        *(float4*)&Z[ldr][cg*4 + j*64] = *(const float4*)(sp + cg*4 + j*64);
    }
    // stage e2 for this book into LDS (512 threads x 4 floats)
    *(float4*)&e2s[tid*4] = *(const float4*)&e2b[tid*4];
    if (tid == 0) { nfull = 0; npair = 0; }
    __syncthreads();                            // S1

    // ---- A fragments from LDS (f32 -> f16): 32 rows, full K ----
    half8_t A[2][8];
    #pragma unroll
    for (int mt = 0; mt < 2; ++mt) {
      #pragma unroll
      for (int ks = 0; ks < 8; ++ks) {
        const float* zp = &Z[mt*16 + ln15][lq*8 + ks*32];
        float4 u = *(const float4*)zp;
        float4 v = *(const float4*)(zp + 4);
        half8_t a;
        a[0]=(_Float16)u.x; a[1]=(_Float16)u.y; a[2]=(_Float16)u.z; a[3]=(_Float16)u.w;
        a[4]=(_Float16)v.x; a[5]=(_Float16)v.y; a[6]=(_Float16)v.z; a[7]=(_Float16)v.w;
        A[mt][ks] = a;
      }
    }

    uint32_t p1[2][4], p2[2][4], p3[2][4];
    #pragma unroll
    for (int mt = 0; mt < 2; ++mt)
      #pragma unroll
      for (int j = 0; j < 4; ++j) {
        p1[mt][j] = 0xFFFFFFFFu; p2[mt][j] = 0xFFFFFFFFu; p3[mt][j] = 0xFFFFFFFFu;
      }

    const _Float16* ebase = E16b + (size_t)(wave*256 + ln15)*DD + lq*8;

    for (int nt = 0; nt < 16; ++nt) {
      const _Float16* bp = ebase + (size_t)nt*16*DD;
      int code = wave*256 + nt*16 + ln15;
      float e2v = e2s[code] - SHIFT;
      f32x4 acc[2];
      acc[0] = (f32x4){0.f,0.f,0.f,0.f};
      acc[1] = (f32x4){0.f,0.f,0.f,0.f};
      // batch 0: ks 0..3
      {
        half8_t B0 = *(const half8_t*)(bp + 0*32);
        half8_t B1 = *(const half8_t*)(bp + 1*32);
        half8_t B2 = *(const half8_t*)(bp + 2*32);
        half8_t B3 = *(const half8_t*)(bp + 3*32);
        acc[0] = __builtin_amdgcn_mfma_f32_16x16x32_f16(A[0][0], B0, acc[0], 0, 0, 0);
        acc[1] = __builtin_amdgcn_mfma_f32_16x16x32_f16(A[1][0], B0, acc[1], 0, 0, 0);
        acc[0] = __builtin_amdgcn_mfma_f32_16x16x32_f16(A[0][1], B1, acc[0], 0, 0, 0);
        acc[1] = __builtin_amdgcn_mfma_f32_16x16x32_f16(A[1][1], B1, acc[1], 0, 0, 0);
        acc[0] = __builtin_amdgcn_mfma_f32_16x16x32_f16(A[0][2], B2, acc[0], 0, 0, 0);
        acc[1] = __builtin_amdgcn_mfma_f32_16x16x32_f16(A[1][2], B2, acc[1], 0, 0, 0);
        acc[0] = __builtin_amdgcn_mfma_f32_16x16x32_f16(A[0][3], B3, acc[0], 0, 0, 0);
        acc[1] = __builtin_amdgcn_mfma_f32_16x16x32_f16(A[1][3], B3, acc[1], 0, 0, 0);
      }
      // batch 1: ks 4..7
      {
        half8_t B4 = *(const half8_t*)(bp + 4*32);
        half8_t B5 = *(const half8_t*)(bp + 5*32);
        half8_t B6 = *(const half8_t*)(bp + 6*32);
        half8_t B7 = *(const half8_t*)(bp + 7*32);
        acc[0] = __builtin_amdgcn_mfma_f32_16x16x32_f16(A[0][4], B4, acc[0], 0, 0, 0);
        acc[1] = __builtin_amdgcn_mfma_f32_16x16x32_f16(A[1][4], B4, acc[1], 0, 0, 0);
        acc[0] = __builtin_amdgcn_mfma_f32_16x16x32_f16(A[0][5], B5, acc[0], 0, 0, 0);
        acc[1] = __builtin_amdgcn_mfma_f32_16x16x32_f16(A[1][5], B5, acc[1], 0, 0, 0);
        acc[0] = __builtin_amdgcn_mfma_f32_16x16x32_f16(A[0][6], B6, acc[0], 0, 0, 0);
        acc[1] = __builtin_amdgcn_mfma_f32_16x16x32_f16(A[1][6], B6, acc[1], 0, 0, 0);
        acc[0] = __builtin_amdgcn_mfma_f32_16x16x32_f16(A[0][7], B7, acc[0], 0, 0, 0);
        acc[1] = __builtin_amdgcn_mfma_f32_16x16x32_f16(A[1][7], B7, acc[1], 0, 0, 0);
      }
      // scores + packed top-3. C/D: col(code)=lane&15, row=(lane>>4)*4+reg
      #pragma unroll
      for (int mt = 0; mt < 2; ++mt)
        #pragma unroll
        for (int j = 0; j < 4; ++j) {
          float u = fmaf(-2.f, acc[mt][j], e2v);
          ins3(p1[mt][j], p2[mt][j], p3[mt][j], packsc(u, code));
        }
    }

    // ---- in-wave reduce over the 16 code-columns, then cross-wave ----
    #pragma unroll
    for (int mt = 0; mt < 2; ++mt)
      #pragma unroll
      for (int j = 0; j < 4; ++j) {
        uint32_t v1 = p1[mt][j], v2 = p2[mt][j], v3 = p3[mt][j];
        #pragma unroll
        for (int m = 1; m <= 8; m <<= 1) {
          uint32_t w1 = (uint32_t)__shfl_xor((int)v1, m);
          uint32_t w2 = (uint32_t)__shfl_xor((int)v2, m);
          uint32_t w3 = (uint32_t)__shfl_xor((int)v3, m);
          ins3(v1, v2, v3, w1);
          ins3(v1, v2, v3, w2);
          ins3(v1, v2, v3, w3);
        }
        if (ln15 == 0) {
          int rl = mt*16 + lq*4 + j;
          L1[wave][rl] = v1; L2[wave][rl] = v2; L3[wave][rl] = v3;
        }
      }
    __syncthreads();                            // S2
    if (tid < RPB) {
      uint32_t v1 = L1[0][tid], v2 = L2[0][tid], v3 = L3[0][tid];
      #pragma unroll
      for (int w = 1; w < 8; ++w) {
        ins3(v1, v2, v3, L1[w][tid]);
        ins3(v1, v2, v3, L2[w][tid]);
        ins3(v1, v2, v3, L3[w][tid]);
      }
      int a1 = (int)(v1 & 2047u), a2 = (int)(v2 & 2047u);
      float f1 = unpacksc(v1), f2 = unpacksc(v2), f3 = unpacksc(v3);
      codes_s[tid] = a1;
      int rg = row0 + tid;
      codes_f[((size_t)(rg >> 12)*NBOOKS + ib)*TT + (rg & (TT-1))] = (float)a1;
      if (ib == 0) codes0[rg] = a1;
      if (f3 - f1 < EPS_FULL) {
        flist[atomicAdd(&nfull, 1)] = tid;
      } else if (f2 - f1 < EPS_PAIR) {
        plist[atomicAdd(&npair, 1)] = tid | (a1 << 6) | (a2 << 17);
      }
    }
    __syncthreads();                            // S3

    // ---- full fp64 re-rank (rare: 3rd-best within EPS of best) ----
    int nfl = nfull;
    for (int f = 0; f < nfl; ++f) {
      int row = flist[f];
      double bestv = DBL_MAX; int besti = 0x7fffffff;
      #pragma unroll
      for (int q = 0; q < 4; ++q) {
        int k = q*512 + tid;
        const float* er = Eb + (size_t)k*DD;
        double s = 0.0;
        for (int d = 0; d < DD; d += 4) {
          float4 e = *(const float4*)(er + d);
          double d0 = (double)Z[row][d+0] - (double)e.x; s += d0*d0;
          double d1 = (double)Z[row][d+1] - (double)e.y; s += d1*d1;
          double d2 = (double)Z[row][d+2] - (double)e.z; s += d2*d2;
          double d3 = (double)Z[row][d+3] - (double)e.w; s += d3*d3;
        }
        if (s < bestv || (s == bestv && k < besti)) { bestv = s; besti = k; }
      }
      #pragma unroll
      for (int m = 1; m <= 32; m <<= 1) {
        double ov = __shfl_xor(bestv, m);
        int    oi = __shfl_xor(besti, m);
        if (ov < bestv || (ov == bestv && oi < besti)) { bestv = ov; besti = oi; }
      }
      if (lane == 0) { Rv[wave] = bestv; Ri[wave] = besti; }
      __syncthreads();
      if (tid == 0) {
        double bvv = Rv[0]; int bii = Ri[0];
        #pragma unroll
        for (int w = 1; w < 8; ++w)
          if (Rv[w] < bvv || (Rv[w] == bvv && Ri[w] < bii)) { bvv = Rv[w]; bii = Ri[w]; }
        codes_s[row] = bii;
        int rg = row0 + row;
        codes_f[((size_t)(rg >> 12)*NBOOKS + ib)*TT + (rg & (TT-1))] = (float)bii;
        if (ib == 0) codes0[rg] = bii;
      }
      __syncthreads();
    }

    // ---- pairwise fp64 refine: one wave per flagged row, compares top-2 ----
    {
      int npr = npair;
      for (int f = wave; f < npr; f += 8) {
        int pk = plist[f];
        int row = pk & 63;
        int c1 = (pk >> 6) & 2047, c2 = (pk >> 17) & 2047;
        int cc = (lane < 32) ? c1 : c2;
        const float* er = Eb + (size_t)cc*DD + (lane & 31)*8;
        const float* zr = &Z[row][(lane & 31)*8];
        double s = 0.0;
        #pragma unroll
        for (int d = 0; d < 8; ++d) {
          double df = (double)zr[d] - (double)er[d];
          s += df*df;
        }
        #pragma unroll
        for (int m = 1; m <= 16; m <<= 1) s += __shfl_xor(s, m);
        double so = __shfl_xor(s, 32);
        double d1 = (lane < 32) ? s : so;
        double d2 = (lane < 32) ? so : s;
        int win = (d2 < d1 || (d2 == d1 && c2 < c1)) ? c2 : c1;
        if (lane == 0) {
          codes_s[row] = win;
          int rg = row0 + row;
          codes_f[((size_t)(rg >> 12)*NBOOKS + ib)*TT + (rg & (TT-1))] = (float)win;
          if (ib == 0) codes0[rg] = win;
        }
      }
    }
    __syncthreads();                            // S4: codes_s final

    // ---- f32 residual subtract in LDS (acoustic books only) ----
    if (ib >= 1) {
      int code = codes_s[sr];
      const float* er = Eb + (size_t)code*DD;
      #pragma unroll
      for (int j = 0; j < 4; ++j) {
        int c = sg*4 + j*64;
        float4 e = *(const float4*)(er + c);
        float4 z = *(const float4*)&Z[sr][c];
        z.x -= e.x; z.y -= e.y; z.z -= e.z; z.w -= e.w;
        *(float4*)&Z[sr][c] = z;
      }
    }
    __syncthreads();                            // S5: Z stable for next book
  }

  // ---- aco = xa_initial - xa_final ----
  {
    const float* xp = xa_g + (size_t)(row0 + ldr)*DD;
    float*       ap = aco_g + (size_t)(row0 + ldr)*DD;
    #pragma unroll
    for (int j = 0; j < 4; ++j) {
      int c = cg*4 + j*64;
      float4 x0 = *(const float4*)(xp + c);
      float4 zf = *(const float4*)&Z[ldr][c];
      float4 o;
      o.x = x0.x - zf.x; o.y = x0.y - zf.y; o.z = x0.z - zf.z; o.w = x0.w - zf.w;
      *(float4*)(ap + c) = o;
    }
  }
}

// ---------------- decode ----------------
__global__ __launch_bounds__(256) void final_kernel(
    const float* __restrict__ Wos, const float* __restrict__ Woa,
    const float* __restrict__ E0, const int* __restrict__ codes0,
    const float* __restrict__ aco, float* __restrict__ out)
{
  __shared__ float wsl[16*68], wal[16*68], sml[16*68], acl[16*68];
  const int tid = threadIdx.x;
  const int t0 = blockIdx.x*64, c0 = blockIdx.y*64, b = blockIdx.z;
  const int u = tid & 63, dq = tid >> 6;
  const int tx = tid & 15, ty = tid >> 4;
  int code = codes0[b*TT + t0 + u];
  const float* smr = E0 + (size_t)code*DD;
  const float* acr = aco + (size_t)(b*TT + t0 + u)*DD;
  const float* wsr = Wos + (size_t)(c0+u)*DD;
  const float* war = Woa + (size_t)(c0+u)*DD;
  float accS[4][4] = {{0}}, accA[4][4] = {{0}};
  for (int dc0 = 0; dc0 < DD; dc0 += 16) {
    __syncthreads();
    float4 v;
    v = *(const float4*)(wsr + dc0 + dq*4);
    wsl[(dq*4+0)*68+u]=v.x; wsl[(dq*4+1)*68+u]=v.y; wsl[(dq*4+2)*68+u]=v.z; wsl[(dq*4+3)*68+u]=v.w;
    v = *(const float4*)(war + dc0 + dq*4);
    wal[(dq*4+0)*68+u]=v.x; wal[(dq*4+1)*68+u]=v.y; wal[(dq*4+2)*68+u]=v.z; wal[(dq*4+3)*68+u]=v.w;
    v = *(const float4*)(smr + dc0 + dq*4);
    sml[(dq*4+0)*68+u]=v.x; sml[(dq*4+1)*68+u]=v.y; sml[(dq*4+2)*68+u]=v.z; sml[(dq*4+3)*68+u]=v.w;
    v = *(const float4*)(acr + dc0 + dq*4);
    acl[(dq*4+0)*68+u]=v.x; acl[(dq*4+1)*68+u]=v.y; acl[(dq*4+2)*68+u]=v.z; acl[(dq*4+3)*68+u]=v.w;
    __syncthreads();
    #pragma unroll
    for (int d = 0; d < 16; ++d) {
      float4 cs = *(const float4*)&wsl[d*68 + tx*4];
      float4 ca = *(const float4*)&wal[d*68 + tx*4];
      float4 ts = *(const float4*)&sml[d*68 + ty*4];
      float4 ta = *(const float4*)&acl[d*68 + ty*4];
      float csf[4]={cs.x,cs.y,cs.z,cs.w}, caf[4]={ca.x,ca.y,ca.z,ca.w};
      float tsf[4]={ts.x,ts.y,ts.z,ts.w}, taf[4]={ta.x,ta.y,ta.z,ta.w};
      #pragma unroll
      for (int i = 0; i < 4; ++i)
        #pragma unroll
        for (int j = 0; j < 4; ++j) {
          accS[i][j] = fmaf(csf[i], tsf[j], accS[i][j]);
          accA[i][j] = fmaf(caf[i], taf[j], accA[i][j]);
        }
    }
  }
  size_t ob = (size_t)b*CC*TT;
  #pragma unroll
  for (int i = 0; i < 4; ++i) {
    float4 r;
    r.x = accS[i][0] + accA[i][0];
    r.y = accS[i][1] + accA[i][1];
    r.z = accS[i][2] + accA[i][2];
    r.w = accS[i][3] + accA[i][3];
    *(float4*)&out[ob + (size_t)(c0 + tx*4 + i)*TT + t0 + ty*4] = r;
  }
}

extern "C" void kernel_launch(void* const* d_in, const int* in_sizes, int n_in,
                              void* d_out, int out_size, void* d_ws, size_t ws_size,
                              hipStream_t stream) {
  const float* x    = (const float*)d_in[0];
  const float* Wins = (const float*)d_in[1];
  const float* Wina = (const float*)d_in[2];
  const float* Wos  = (const float*)d_in[3];
  const float* Woa  = (const float*)d_in[4];
  const float* E    = (const float*)d_in[5];
  float* out = (float*)d_out;
  float* codes_f = out + (size_t)BB*CC*TT;

  // E16 plane lives in the front of d_out (18.9MB; codes_f starts at 33.6MB;
  // out[0:8.4M floats] fully overwritten by final_kernel afterwards).
  _Float16* E16 = (_Float16*)d_out;

  float* xs  = (float*)d_ws;
  float* xa  = xs + (size_t)MM*DD;
  float* aco = xa + (size_t)MM*DD;
  float* e2  = aco + (size_t)MM*DD;
  int* codes_i = (int*)(e2 + 18*KK);

  proj_kernel<<<dim3(TT/64, DD/64, BB), 256, 0, stream>>>(x, Wins, Wina, xs, xa);
  e2_kernel<<<(18*KK*64)/256, 256, 0, stream>>>(E, e2);
  cvt_e16_kernel<<<(18*KK*DD)/8/256, 256, 0, stream>>>(E, E16);

  fused_encode_kernel<<<MM/RPB, 512, 0, stream>>>(xs, xa, E, E16, e2,
                                                  codes_i, codes_f, aco);

  final_kernel<<<dim3(TT/64, CC/64, BB), 256, 0, stream>>>(Wos, Woa, E, codes_i, aco, out);
}

// Round 17
// 2001.366 us; speedup vs baseline: 1.5075x; 1.1184x over previous
//
#include <hip/hip_runtime.h>
#include <float.h>

#define TT 4096
#define BB 4
#define CC 512
#define DD 256
#define KK 2048
#define MM (BB*TT)        // 16384 rows (b,t)
#define NBOOKS 22
#define EPS_PAIR 0.5f
#define EPS_FULL 0.5f
#define ZSTR 260          // 260 % 32 == 4 -> conflict-light
#define RPB 32            // rows per block

typedef _Float16 half8_t __attribute__((ext_vector_type(8)));
typedef float f32x4 __attribute__((ext_vector_type(4)));

// ---- packed-u32 top-3 tracking ----
// key = monotone(float) with low 11 bits replaced by code index.
__device__ __forceinline__ uint32_t packsc(float s, int code) {
  uint32_t b = __float_as_uint(s);
  uint32_t key = b ^ ((uint32_t)((int32_t)b >> 31) | 0x80000000u);
  return (key & 0xFFFFF800u) | (uint32_t)code;
}
__device__ __forceinline__ float unpacksc(uint32_t p) {
  uint32_t key = p & 0xFFFFF800u;
  uint32_t b = (key & 0x80000000u) ? (key ^ 0x80000000u) : ~key;
  return __uint_as_float(b);
}
// branchless insert into sorted triple (5 min/max ops)
__device__ __forceinline__ void ins3(uint32_t& v1, uint32_t& v2, uint32_t& v3,
                                     uint32_t p) {
  uint32_t t1 = max(v1, p); v1 = min(v1, p);
  uint32_t t2 = max(v2, t1); v2 = min(v2, t1);
  v3 = min(v3, t2);
}

// ---------------- projection: xs = Win_s @ x, xa = Win_a @ x ----------------
__global__ __launch_bounds__(256) void proj_kernel(const float* __restrict__ x,
    const float* __restrict__ Ws, const float* __restrict__ Wa,
    float* __restrict__ xs, float* __restrict__ xa)
{
  __shared__ float xt[16*64];
  __shared__ float wsl[16*68];
  __shared__ float wal[16*68];
  const int tid = threadIdx.x;
  const int t0 = blockIdx.x*64, d0 = blockIdx.y*64, b = blockIdx.z;
  const int u = tid & 63, cq = tid >> 6;
  const int tx = tid & 15, ty = tid >> 4;
  const float* xb = x + (size_t)b*CC*TT;
  float accS[4][4] = {{0}}, accA[4][4] = {{0}};
  for (int c0 = 0; c0 < CC; c0 += 16) {
    __syncthreads();
    #pragma unroll
    for (int i = 0; i < 4; ++i) {
      int cc = cq*4 + i;
      xt[cc*64 + u] = xb[(size_t)(c0+cc)*TT + t0 + u];
    }
    {
      float4 wv = *(const float4*)&Ws[(size_t)(d0+u)*CC + c0 + cq*4];
      wsl[(cq*4+0)*68 + u] = wv.x; wsl[(cq*4+1)*68 + u] = wv.y;
      wsl[(cq*4+2)*68 + u] = wv.z; wsl[(cq*4+3)*68 + u] = wv.w;
      wv = *(const float4*)&Wa[(size_t)(d0+u)*CC + c0 + cq*4];
      wal[(cq*4+0)*68 + u] = wv.x; wal[(cq*4+1)*68 + u] = wv.y;
      wal[(cq*4+2)*68 + u] = wv.z; wal[(cq*4+3)*68 + u] = wv.w;
    }
    __syncthreads();
    #pragma unroll
    for (int cc = 0; cc < 16; ++cc) {
      float4 tq = *(const float4*)&xt[cc*64 + ty*4];
      float4 sq = *(const float4*)&wsl[cc*68 + tx*4];
      float4 aq = *(const float4*)&wal[cc*68 + tx*4];
      float tf[4] = {tq.x,tq.y,tq.z,tq.w};
      float sf[4] = {sq.x,sq.y,sq.z,sq.w};
      float af[4] = {aq.x,aq.y,aq.z,aq.w};
      #pragma unroll
      for (int i = 0; i < 4; ++i)
        #pragma unroll
        for (int j = 0; j < 4; ++j) {
          accS[i][j] = fmaf(tf[i], sf[j], accS[i][j]);
          accA[i][j] = fmaf(tf[i], af[j], accA[i][j]);
        }
    }
  }
  #pragma unroll
  for (int i = 0; i < 4; ++i) {
    size_t r = (size_t)b*TT + t0 + ty*4 + i;
    float4 o;
    o.x = accS[i][0]; o.y = accS[i][1]; o.z = accS[i][2]; o.w = accS[i][3];
    *(float4*)&xs[r*DD + d0 + tx*4] = o;
    o.x = accA[i][0]; o.y = accA[i][1]; o.z = accA[i][2]; o.w = accA[i][3];
    *(float4*)&xa[r*DD + d0 + tx*4] = o;
  }
}

// ---------------- e2[k] = sum_d E[k][d]^2 ----------------
__global__ __launch_bounds__(256) void e2_kernel(const float* __restrict__ E,
    float* __restrict__ e2)
{
  int gid = blockIdx.x*256 + threadIdx.x;
  int wid = gid >> 6, lane = gid & 63;
  if (wid < 18*KK) {
    float4 v = *(const float4*)&E[(size_t)wid*DD + lane*4];
    float s = v.x*v.x + v.y*v.y + v.z*v.z + v.w*v.w;
    #pragma unroll
    for (int m = 1; m <= 32; m <<= 1) s += __shfl_xor(s, m);
    if (lane == 0) e2[wid] = s;
  }
}

// ---------------- convert E -> f16 plane ----------------
__global__ __launch_bounds__(256) void cvt_e16_kernel(const float* __restrict__ E,
    _Float16* __restrict__ E16)
{
  size_t i = ((size_t)blockIdx.x*256 + threadIdx.x)*8;
  float4 u = *(const float4*)&E[i];
  float4 v = *(const float4*)&E[i+4];
  half8_t h;
  h[0]=(_Float16)u.x; h[1]=(_Float16)u.y; h[2]=(_Float16)u.z; h[3]=(_Float16)u.w;
  h[4]=(_Float16)v.x; h[5]=(_Float16)v.y; h[6]=(_Float16)v.z; h[7]=(_Float16)v.w;
  *(half8_t*)&E16[i] = h;
}

// compute one 16-code tile: 16 MFMA (two chains) + scores + top-3
__device__ __forceinline__ void tile_compute(
    const half8_t A[2][8], const half8_t B[8], float e2v, int code,
    uint32_t p1[2][4], uint32_t p2[2][4], uint32_t p3[2][4])
{
  f32x4 a0 = (f32x4){0.f,0.f,0.f,0.f};
  f32x4 a1 = (f32x4){0.f,0.f,0.f,0.f};
  #pragma unroll
  for (int ks = 0; ks < 8; ++ks) {
    a0 = __builtin_amdgcn_mfma_f32_16x16x32_f16(A[0][ks], B[ks], a0, 0, 0, 0);
    a1 = __builtin_amdgcn_mfma_f32_16x16x32_f16(A[1][ks], B[ks], a1, 0, 0, 0);
  }
  // C/D: col(code)=lane&15, row=(lane>>4)*4+reg
  #pragma unroll
  for (int j = 0; j < 4; ++j) {
    float u0 = fmaf(-2.f, a0[j], e2v);
    ins3(p1[0][j], p2[0][j], p3[0][j], packsc(u0, code));
    float u1 = fmaf(-2.f, a1[j], e2v);
    ins3(p1[1][j], p2[1][j], p3[1][j], packsc(u1, code));
  }
}

// ---------------- FUSED encode: all 22 books, one kernel ----------------
// 512 blocks x 32 rows, 256 threads = 4 waves (the proven shape). Per wave:
// A[2][8] (32 rows, 64 VGPR) x 512-code quarter. waves_per_eu(1): the only
// hint that allocates >= demand (ledger: r10 gave 180, no spill); grid =
// 2 blocks/CU keeps 2 waves/SIMD residency regardless. The key change vs
// r14: a 2-stage register double-buffer (B0/B1) so every 8-load batch has
// a full compute phase to land -> load latency off the critical path.
__global__ __launch_bounds__(256) __attribute__((amdgpu_waves_per_eu(1)))
void fused_encode_kernel(
    const float* __restrict__ xs_g, const float* __restrict__ xa_g,
    const float* __restrict__ E, const _Float16* __restrict__ E16,
    const float* __restrict__ e2, int* __restrict__ codes0,
    float* __restrict__ codes_f, float* __restrict__ aco_g)
{
  const int tid = threadIdx.x;
  const int lane = tid & 63, wave = tid >> 6;   // 4 waves
  const int ln15 = lane & 15, lq = lane >> 4;   // lq 0..3
  const int row0 = blockIdx.x * RPB;

  __shared__ float Z[RPB][ZSTR];                // residual panel (~33KB)
  __shared__ float e2s[KK];                     // e2 for this book (8KB)
  __shared__ uint32_t L1[4][RPB], L2[4][RPB], L3[4][RPB];
  __shared__ int   codes_s[RPB];
  __shared__ int   flist[RPB], plist[RPB];
  __shared__ int   nfull, npair;
  __shared__ double Rv[4];
  __shared__ int    Ri[4];

  const int ldr = tid & 31, cg = tid >> 5;      // panel-load / aco mapping
  const int sr = tid >> 3, sg = tid & 7;        // subtract mapping (8 thr/row)

  for (int ib = 0; ib < NBOOKS; ++ib) {
    const int book = (ib <= 17) ? ib : 17;
    const float*     Eb   = E   + (size_t)book*KK*DD;
    const _Float16*  E16b = E16 + (size_t)book*KK*DD;
    const float*     e2b  = e2  + (size_t)book*KK;

    if (ib <= 1) {                              // ib0: xs panel; ib1: xa panel
      const float* src = (ib == 0) ? xs_g : xa_g;
      const float* sp = src + (size_t)(row0 + ldr)*DD + cg*32;
      #pragma unroll
      for (int j = 0; j < 8; ++j)
        *(float4*)&Z[ldr][cg*32 + j*4] = *(const float4*)(sp + j*4);
    }
    // stage e2 for this book into LDS (256 threads x 8 floats)
    {
      *(float4*)&e2s[tid*8]     = *(const float4*)&e2b[tid*8];
      *(float4*)&e2s[tid*8 + 4] = *(const float4*)&e2b[tid*8 + 4];
    }
    if (tid == 0) { nfull = 0; npair = 0; }
    __syncthreads();                            // S1

    // ---- A fragments from LDS (f32 -> f16): 32 rows, full K ----
    half8_t A[2][8];
    #pragma unroll
    for (int mt = 0; mt < 2; ++mt) {
      #pragma unroll
      for (int ks = 0; ks < 8; ++ks) {
        const float* zp = &Z[mt*16 + ln15][lq*8 + ks*32];
        float4 u = *(const float4*)zp;
        float4 v = *(const float4*)(zp + 4);
        half8_t a;
        a[0]=(_Float16)u.x; a[1]=(_Float16)u.y; a[2]=(_Float16)u.z; a[3]=(_Float16)u.w;
        a[4]=(_Float16)v.x; a[5]=(_Float16)v.y; a[6]=(_Float16)v.z; a[7]=(_Float16)v.w;
        A[mt][ks] = a;
      }
    }

    uint32_t p1[2][4], p2[2][4], p3[2][4];
    #pragma unroll
    for (int mt = 0; mt < 2; ++mt)
      #pragma unroll
      for (int j = 0; j < 4; ++j) {
        p1[mt][j] = 0xFFFFFFFFu; p2[mt][j] = 0xFFFFFFFFu; p3[mt][j] = 0xFFFFFFFFu;
      }

    const _Float16* ebase = E16b + (size_t)(wave*512 + ln15)*DD + lq*8;

    // ---- 2-stage register double-buffered search over 32 nt ----
    half8_t B0[8], B1[8];
    #pragma unroll
    for (int ks = 0; ks < 8; ++ks) B0[ks] = *(const half8_t*)(ebase + ks*32);

    for (int nt = 0; nt < 32; nt += 2) {
      const _Float16* bp1 = ebase + (size_t)(nt+1)*16*DD;
      #pragma unroll
      for (int ks = 0; ks < 8; ++ks) B1[ks] = *(const half8_t*)(bp1 + ks*32);

      int code0 = wave*512 + nt*16 + ln15;
      tile_compute(A, B0, e2s[code0], code0, p1, p2, p3);

      if (nt + 2 < 32) {
        const _Float16* bp2 = ebase + (size_t)(nt+2)*16*DD;
        #pragma unroll
        for (int ks = 0; ks < 8; ++ks) B0[ks] = *(const half8_t*)(bp2 + ks*32);
      }

      int code1 = wave*512 + (nt+1)*16 + ln15;
      tile_compute(A, B1, e2s[code1], code1, p1, p2, p3);
    }

    // ---- in-wave reduce over the 16 code-columns, then cross-wave ----
    #pragma unroll
    for (int mt = 0; mt < 2; ++mt)
      #pragma unroll
      for (int j = 0; j < 4; ++j) {
        uint32_t v1 = p1[mt][j], v2 = p2[mt][j], v3 = p3[mt][j];
        #pragma unroll
        for (int m = 1; m <= 8; m <<= 1) {
          uint32_t w1 = (uint32_t)__shfl_xor((int)v1, m);
          uint32_t w2 = (uint32_t)__shfl_xor((int)v2, m);
          uint32_t w3 = (uint32_t)__shfl_xor((int)v3, m);
          ins3(v1, v2, v3, w1);
          ins3(v1, v2, v3, w2);
          ins3(v1, v2, v3, w3);
        }
        if (ln15 == 0) {
          int rl = mt*16 + lq*4 + j;
          L1[wave][rl] = v1; L2[wave][rl] = v2; L3[wave][rl] = v3;
        }
      }
    __syncthreads();                            // S2
    if (tid < RPB) {
      uint32_t v1 = L1[0][tid], v2 = L2[0][tid], v3 = L3[0][tid];
      #pragma unroll
      for (int w = 1; w < 4; ++w) {
        ins3(v1, v2, v3, L1[w][tid]);
        ins3(v1, v2, v3, L2[w][tid]);
        ins3(v1, v2, v3, L3[w][tid]);
      }
      int a1 = (int)(v1 & 2047u), a2 = (int)(v2 & 2047u);
      float f1 = unpacksc(v1), f2 = unpacksc(v2), f3 = unpacksc(v3);
      codes_s[tid] = a1;
      int rg = row0 + tid;
      codes_f[((size_t)(rg >> 12)*NBOOKS + ib)*TT + (rg & (TT-1))] = (float)a1;
      if (ib == 0) codes0[rg] = a1;
      if (f3 - f1 < EPS_FULL) {
        flist[atomicAdd(&nfull, 1)] = tid;
      } else if (f2 - f1 < EPS_PAIR) {
        plist[atomicAdd(&npair, 1)] = tid | (a1 << 6) | (a2 << 17);
      }
    }
    __syncthreads();                            // S3

    // ---- full fp64 re-rank (rare: 3rd-best within EPS of best) ----
    int nfl = nfull;
    for (int f = 0; f < nfl; ++f) {
      int row = flist[f];
      double bestv = DBL_MAX; int besti = 0x7fffffff;
      #pragma unroll
      for (int q = 0; q < 8; ++q) {
        int k = q*256 + tid;
        const float* er = Eb + (size_t)k*DD;
        double s = 0.0;
        for (int d = 0; d < DD; d += 4) {
          float4 e = *(const float4*)(er + d);
          double d0 = (double)Z[row][d+0] - (double)e.x; s += d0*d0;
          double d1 = (double)Z[row][d+1] - (double)e.y; s += d1*d1;
          double d2 = (double)Z[row][d+2] - (double)e.z; s += d2*d2;
          double d3 = (double)Z[row][d+3] - (double)e.w; s += d3*d3;
        }
        if (s < bestv || (s == bestv && k < besti)) { bestv = s; besti = k; }
      }
      #pragma unroll
      for (int m = 1; m <= 32; m <<= 1) {
        double ov = __shfl_xor(bestv, m);
        int    oi = __shfl_xor(besti, m);
        if (ov < bestv || (ov == bestv && oi < besti)) { bestv = ov; besti = oi; }
      }
      if (lane == 0) { Rv[wave] = bestv; Ri[wave] = besti; }
      __syncthreads();
      if (tid == 0) {
        double bvv = Rv[0]; int bii = Ri[0];
        #pragma unroll
        for (int w = 1; w < 4; ++w)
          if (Rv[w] < bvv || (Rv[w] == bvv && Ri[w] < bii)) { bvv = Rv[w]; bii = Ri[w]; }
        codes_s[row] = bii;
        int rg = row0 + row;
        codes_f[((size_t)(rg >> 12)*NBOOKS + ib)*TT + (rg & (TT-1))] = (float)bii;
        if (ib == 0) codes0[rg] = bii;
      }
      __syncthreads();
    }

    // ---- pairwise fp64 refine: one wave per flagged row, compares top-2 ----
    {
      int npr = npair;
      for (int f = wave; f < npr; f += 4) {
        int pk = plist[f];
        int row = pk & 63;
        int c1 = (pk >> 6) & 2047, c2 = (pk >> 17) & 2047;
        int cc = (lane < 32) ? c1 : c2;
        const float* er = Eb + (size_t)cc*DD + (lane & 31)*8;
        const float* zr = &Z[row][(lane & 31)*8];
        double s = 0.0;
        #pragma unroll
        for (int d = 0; d < 8; ++d) {
          double df = (double)zr[d] - (double)er[d];
          s += df*df;
        }
        #pragma unroll
        for (int m = 1; m <= 16; m <<= 1) s += __shfl_xor(s, m);
        double so = __shfl_xor(s, 32);
        double d1 = (lane < 32) ? s : so;
        double d2 = (lane < 32) ? so : s;
        int win = (d2 < d1 || (d2 == d1 && c2 < c1)) ? c2 : c1;
        if (lane == 0) {
          codes_s[row] = win;
          int rg = row0 + row;
          codes_f[((size_t)(rg >> 12)*NBOOKS + ib)*TT + (rg & (TT-1))] = (float)win;
          if (ib == 0) codes0[rg] = win;
        }
      }
    }
    __syncthreads();                            // S4: codes_s final

    // ---- f32 residual subtract in LDS (acoustic books only) ----
    if (ib >= 1) {
      int code = codes_s[sr];
      const float* er = Eb + (size_t)code*DD;
      #pragma unroll
      for (int j = 0; j < 8; ++j) {
        int c = sg*4 + j*32;
        float4 e = *(const float4*)(er + c);
        float4 z = *(const float4*)&Z[sr][c];
        z.x -= e.x; z.y -= e.y; z.z -= e.z; z.w -= e.w;
        *(float4*)&Z[sr][c] = z;
      }
    }
    __syncthreads();                            // S5: Z stable for next book
  }

  // ---- aco = xa_initial - xa_final ----
  {
    const float* xp = xa_g + (size_t)(row0 + ldr)*DD + cg*32;
    float*       ap = aco_g + (size_t)(row0 + ldr)*DD + cg*32;
    #pragma unroll
    for (int j = 0; j < 8; ++j) {
      float4 x0 = *(const float4*)(xp + j*4);
      float4 zf = *(const float4*)&Z[ldr][cg*32 + j*4];
      float4 o;
      o.x = x0.x - zf.x; o.y = x0.y - zf.y; o.z = x0.z - zf.z; o.w = x0.w - zf.w;
      *(float4*)(ap + j*4) = o;
    }
  }
}

// ---------------- decode ----------------
__global__ __launch_bounds__(256) void final_kernel(
    const float* __restrict__ Wos, const float* __restrict__ Woa,
    const float* __restrict__ E0, const int* __restrict__ codes0,
    const float* __restrict__ aco, float* __restrict__ out)
{
  __shared__ float wsl[16*68], wal[16*68], sml[16*68], acl[16*68];
  const int tid = threadIdx.x;
  const int t0 = blockIdx.x*64, c0 = blockIdx.y*64, b = blockIdx.z;
  const int u = tid & 63, dq = tid >> 6;
  const int tx = tid & 15, ty = tid >> 4;
  int code = codes0[b*TT + t0 + u];
  const float* smr = E0 + (size_t)code*DD;
  const float* acr = aco + (size_t)(b*TT + t0 + u)*DD;
  const float* wsr = Wos + (size_t)(c0+u)*DD;
  const float* war = Woa + (size_t)(c0+u)*DD;
  float accS[4][4] = {{0}}, accA[4][4] = {{0}};
  for (int dc0 = 0; dc0 < DD; dc0 += 16) {
    __syncthreads();
    float4 v;
    v = *(const float4*)(wsr + dc0 + dq*4);
    wsl[(dq*4+0)*68+u]=v.x; wsl[(dq*4+1)*68+u]=v.y; wsl[(dq*4+2)*68+u]=v.z; wsl[(dq*4+3)*68+u]=v.w;
    v = *(const float4*)(war + dc0 + dq*4);
    wal[(dq*4+0)*68+u]=v.x; wal[(dq*4+1)*68+u]=v.y; wal[(dq*4+2)*68+u]=v.z; wal[(dq*4+3)*68+u]=v.w;
    v = *(const float4*)(smr + dc0 + dq*4);
    sml[(dq*4+0)*68+u]=v.x; sml[(dq*4+1)*68+u]=v.y; sml[(dq*4+2)*68+u]=v.z; sml[(dq*4+3)*68+u]=v.w;
    v = *(const float4*)(acr + dc0 + dq*4);
    acl[(dq*4+0)*68+u]=v.x; acl[(dq*4+1)*68+u]=v.y; acl[(dq*4+2)*68+u]=v.z; acl[(dq*4+3)*68+u]=v.w;
    __syncthreads();
    #pragma unroll
    for (int d = 0; d < 16; ++d) {
      float4 cs = *(const float4*)&wsl[d*68 + tx*4];
      float4 ca = *(const float4*)&wal[d*68 + tx*4];
      float4 ts = *(const float4*)&sml[d*68 + ty*4];
      float4 ta = *(const float4*)&acl[d*68 + ty*4];
      float csf[4]={cs.x,cs.y,cs.z,cs.w}, caf[4]={ca.x,ca.y,ca.z,ca.w};
      float tsf[4]={ts.x,ts.y,ts.z,ts.w}, taf[4]={ta.x,ta.y,ta.z,ta.w};
      #pragma unroll
      for (int i = 0; i < 4; ++i)
        #pragma unroll
        for (int j = 0; j < 4; ++j) {
          accS[i][j] = fmaf(csf[i], tsf[j], accS[i][j]);
          accA[i][j] = fmaf(caf[i], taf[j], accA[i][j]);
        }
    }
  }
  size_t ob = (size_t)b*CC*TT;
  #pragma unroll
  for (int i = 0; i < 4; ++i) {
    float4 r;
    r.x = accS[i][0] + accA[i][0];
    r.y = accS[i][1] + accA[i][1];
    r.z = accS[i][2] + accA[i][2];
    r.w = accS[i][3] + accA[i][3];
    *(float4*)&out[ob + (size_t)(c0 + tx*4 + i)*TT + t0 + ty*4] = r;
  }
}

extern "C" void kernel_launch(void* const* d_in, const int* in_sizes, int n_in,
                              void* d_out, int out_size, void* d_ws, size_t ws_size,
                              hipStream_t stream) {
  const float* x    = (const float*)d_in[0];
  const float* Wins = (const float*)d_in[1];
  const float* Wina = (const float*)d_in[2];
  const float* Wos  = (const float*)d_in[3];
  const float* Woa  = (const float*)d_in[4];
  const float* E    = (const float*)d_in[5];
  float* out = (float*)d_out;
  float* codes_f = out + (size_t)BB*CC*TT;

  // E16 plane lives in the front of d_out (18.9MB; codes_f starts at 33.6MB;
  // out[0:8.4M floats] fully overwritten by final_kernel afterwards).
  _Float16* E16 = (_Float16*)d_out;

  float* xs  = (float*)d_ws;
  float* xa  = xs + (size_t)MM*DD;
  float* aco = xa + (size_t)MM*DD;
  float* e2  = aco + (size_t)MM*DD;
  int* codes_i = (int*)(e2 + 18*KK);

  proj_kernel<<<dim3(TT/64, DD/64, BB), 256, 0, stream>>>(x, Wins, Wina, xs, xa);
  e2_kernel<<<(18*KK*64)/256, 256, 0, stream>>>(E, e2);
  cvt_e16_kernel<<<(18*KK*DD)/8/256, 256, 0, stream>>>(E, E16);

  fused_encode_kernel<<<MM/RPB, 256, 0, stream>>>(xs, xa, E, E16, e2,
                                                  codes_i, codes_f, aco);

  final_kernel<<<dim3(TT/64, CC/64, BB), 256, 0, stream>>>(Wos, Woa, E, codes_i, aco, out);
}

// Round 18
// 1800.009 us; speedup vs baseline: 1.6761x; 1.1119x over previous
//
#include <hip/hip_runtime.h>
#include <float.h>

#define TT 4096
#define BB 4
#define CC 512
#define DD 256
#define KK 2048
#define MM (BB*TT)        // 16384 rows (b,t)
#define NBOOKS 22
#define EPS_PAIR 0.5f
#define EPS_FULL 0.5f
#define ZSTR 260          // 260 % 32 == 4 -> conflict-light (f32 panel)
#define ASTR 264          // f16 panel stride: 528B rows -> 2-way (free) on frag reads
#define RPB 32            // rows per block

typedef _Float16 half8_t __attribute__((ext_vector_type(8)));
typedef float f32x4 __attribute__((ext_vector_type(4)));

// ---- packed-u32 top-3 tracking ----
__device__ __forceinline__ uint32_t packsc(float s, int code) {
  uint32_t b = __float_as_uint(s);
  uint32_t key = b ^ ((uint32_t)((int32_t)b >> 31) | 0x80000000u);
  return (key & 0xFFFFF800u) | (uint32_t)code;
}
__device__ __forceinline__ float unpacksc(uint32_t p) {
  uint32_t key = p & 0xFFFFF800u;
  uint32_t b = (key & 0x80000000u) ? (key ^ 0x80000000u) : ~key;
  return __uint_as_float(b);
}
__device__ __forceinline__ void ins3(uint32_t& v1, uint32_t& v2, uint32_t& v3,
                                     uint32_t p) {
  uint32_t t1 = max(v1, p); v1 = min(v1, p);
  uint32_t t2 = max(v2, t1); v2 = min(v2, t1);
  v3 = min(v3, t2);
}

// ---------------- projection: xs = Win_s @ x, xa = Win_a @ x ----------------
__global__ __launch_bounds__(256) void proj_kernel(const float* __restrict__ x,
    const float* __restrict__ Ws, const float* __restrict__ Wa,
    float* __restrict__ xs, float* __restrict__ xa)
{
  __shared__ float xt[16*64];
  __shared__ float wsl[16*68];
  __shared__ float wal[16*68];
  const int tid = threadIdx.x;
  const int t0 = blockIdx.x*64, d0 = blockIdx.y*64, b = blockIdx.z;
  const int u = tid & 63, cq = tid >> 6;
  const int tx = tid & 15, ty = tid >> 4;
  const float* xb = x + (size_t)b*CC*TT;
  float accS[4][4] = {{0}}, accA[4][4] = {{0}};
  for (int c0 = 0; c0 < CC; c0 += 16) {
    __syncthreads();
    #pragma unroll
    for (int i = 0; i < 4; ++i) {
      int cc = cq*4 + i;
      xt[cc*64 + u] = xb[(size_t)(c0+cc)*TT + t0 + u];
    }
    {
      float4 wv = *(const float4*)&Ws[(size_t)(d0+u)*CC + c0 + cq*4];
      wsl[(cq*4+0)*68 + u] = wv.x; wsl[(cq*4+1)*68 + u] = wv.y;
      wsl[(cq*4+2)*68 + u] = wv.z; wsl[(cq*4+3)*68 + u] = wv.w;
      wv = *(const float4*)&Wa[(size_t)(d0+u)*CC + c0 + cq*4];
      wal[(cq*4+0)*68 + u] = wv.x; wal[(cq*4+1)*68 + u] = wv.y;
      wal[(cq*4+2)*68 + u] = wv.z; wal[(cq*4+3)*68 + u] = wv.w;
    }
    __syncthreads();
    #pragma unroll
    for (int cc = 0; cc < 16; ++cc) {
      float4 tq = *(const float4*)&xt[cc*64 + ty*4];
      float4 sq = *(const float4*)&wsl[cc*68 + tx*4];
      float4 aq = *(const float4*)&wal[cc*68 + tx*4];
      float tf[4] = {tq.x,tq.y,tq.z,tq.w};
      float sf[4] = {sq.x,sq.y,sq.z,sq.w};
      float af[4] = {aq.x,aq.y,aq.z,aq.w};
      #pragma unroll
      for (int i = 0; i < 4; ++i)
        #pragma unroll
        for (int j = 0; j < 4; ++j) {
          accS[i][j] = fmaf(tf[i], sf[j], accS[i][j]);
          accA[i][j] = fmaf(tf[i], af[j], accA[i][j]);
        }
    }
  }
  #pragma unroll
  for (int i = 0; i < 4; ++i) {
    size_t r = (size_t)b*TT + t0 + ty*4 + i;
    float4 o;
    o.x = accS[i][0]; o.y = accS[i][1]; o.z = accS[i][2]; o.w = accS[i][3];
    *(float4*)&xs[r*DD + d0 + tx*4] = o;
    o.x = accA[i][0]; o.y = accA[i][1]; o.z = accA[i][2]; o.w = accA[i][3];
    *(float4*)&xa[r*DD + d0 + tx*4] = o;
  }
}

// ---------------- e2[k] = sum_d E[k][d]^2 ----------------
__global__ __launch_bounds__(256) void e2_kernel(const float* __restrict__ E,
    float* __restrict__ e2)
{
  int gid = blockIdx.x*256 + threadIdx.x;
  int wid = gid >> 6, lane = gid & 63;
  if (wid < 18*KK) {
    float4 v = *(const float4*)&E[(size_t)wid*DD + lane*4];
    float s = v.x*v.x + v.y*v.y + v.z*v.z + v.w*v.w;
    #pragma unroll
    for (int m = 1; m <= 32; m <<= 1) s += __shfl_xor(s, m);
    if (lane == 0) e2[wid] = s;
  }
}

// ---------------- convert E -> f16 plane ----------------
__global__ __launch_bounds__(256) void cvt_e16_kernel(const float* __restrict__ E,
    _Float16* __restrict__ E16)
{
  size_t i = ((size_t)blockIdx.x*256 + threadIdx.x)*8;
  float4 u = *(const float4*)&E[i];
  float4 v = *(const float4*)&E[i+4];
  half8_t h;
  h[0]=(_Float16)u.x; h[1]=(_Float16)u.y; h[2]=(_Float16)u.z; h[3]=(_Float16)u.w;
  h[4]=(_Float16)v.x; h[5]=(_Float16)v.y; h[6]=(_Float16)v.z; h[7]=(_Float16)v.w;
  *(half8_t*)&E16[i] = h;
}

// ---------------- FUSED encode: all 22 books, one kernel ----------------
// 512 blocks x 32 rows, 256 threads = 4 waves. KEY CHANGE vs r14/r17:
// A fragments live in LDS (A16 panel, identical across waves), ds_read per
// nt -> register demand ~100 (B dbuf 32 + acc 8 + track 24 + addr) -> NO
// SPILL at any allocator cap. LDS 52KB -> 3 blocks/CU = 3 waves/SIMD.
__global__ __launch_bounds__(256)
void fused_encode_kernel(
    const float* __restrict__ xs_g, const float* __restrict__ xa_g,
    const float* __restrict__ E, const _Float16* __restrict__ E16,
    const float* __restrict__ e2, int* __restrict__ codes0,
    float* __restrict__ codes_f, float* __restrict__ aco_g)
{
  const int tid = threadIdx.x;
  const int lane = tid & 63, wave = tid >> 6;   // 4 waves
  const int ln15 = lane & 15, lq = lane >> 4;   // lq 0..3
  const int row0 = blockIdx.x * RPB;

  __shared__ float Z[RPB][ZSTR];                // residual panel f32 (~33.3KB)
  __shared__ _Float16 A16[RPB][ASTR];           // f16 fragment panel (~16.9KB)
  __shared__ uint32_t L1[4][RPB], L2[4][RPB], L3[4][RPB];
  __shared__ int   codes_s[RPB];
  __shared__ int   flist[RPB], plist[RPB];
  __shared__ int   nfull, npair;
  __shared__ double Rv[4];
  __shared__ int    Ri[4];

  const int ldr = tid & 31, cg = tid >> 5;      // panel-load / aco mapping
  const int sr = tid >> 3, sg = tid & 7;        // subtract mapping (8 thr/row)
  const int vr = tid >> 3, vc = (tid & 7)*32;   // convert mapping (32 f per thr)

  for (int ib = 0; ib < NBOOKS; ++ib) {
    const int book = (ib <= 17) ? ib : 17;
    const float*     Eb   = E   + (size_t)book*KK*DD;
    const _Float16*  E16b = E16 + (size_t)book*KK*DD;
    const float*     e2b  = e2  + (size_t)book*KK;

    if (ib <= 1) {                              // ib0: xs panel; ib1: xa panel
      const float* src = (ib == 0) ? xs_g : xa_g;
      const float* sp = src + (size_t)(row0 + ldr)*DD + cg*32;
      #pragma unroll
      for (int j = 0; j < 8; ++j)
        *(float4*)&Z[ldr][cg*32 + j*4] = *(const float4*)(sp + j*4);
    }
    if (tid == 0) { nfull = 0; npair = 0; }
    __syncthreads();                            // S1: Z current

    // ---- convert Z -> A16 (f32 -> f16 panel in LDS) ----
    #pragma unroll
    for (int j = 0; j < 4; ++j) {
      float4 u = *(const float4*)&Z[vr][vc + j*8];
      float4 v = *(const float4*)&Z[vr][vc + j*8 + 4];
      half8_t h;
      h[0]=(_Float16)u.x; h[1]=(_Float16)u.y; h[2]=(_Float16)u.z; h[3]=(_Float16)u.w;
      h[4]=(_Float16)v.x; h[5]=(_Float16)v.y; h[6]=(_Float16)v.z; h[7]=(_Float16)v.w;
      *(half8_t*)&A16[vr][vc + j*8] = h;
    }
    __syncthreads();                            // S1b: A16 ready

    uint32_t p1[2][4], p2[2][4], p3[2][4];
    #pragma unroll
    for (int mt = 0; mt < 2; ++mt)
      #pragma unroll
      for (int j = 0; j < 4; ++j) {
        p1[mt][j] = 0xFFFFFFFFu; p2[mt][j] = 0xFFFFFFFFu; p3[mt][j] = 0xFFFFFFFFu;
      }

    const _Float16* ebase = E16b + (size_t)(wave*512 + ln15)*DD + lq*8;

    // ---- search: B register double-buffer, A from LDS per tile ----
    half8_t B0[8], B1[8];
    #pragma unroll
    for (int ks = 0; ks < 8; ++ks) B0[ks] = *(const half8_t*)(ebase + ks*32);

    for (int nt = 0; nt < 32; nt += 2) {
      const _Float16* bp1 = ebase + (size_t)(nt+1)*16*DD;
      #pragma unroll
      for (int ks = 0; ks < 8; ++ks) B1[ks] = *(const half8_t*)(bp1 + ks*32);
      {
        int code = wave*512 + nt*16 + ln15;
        float e2v = e2b[code];
        f32x4 a0 = (f32x4){0.f,0.f,0.f,0.f};
        f32x4 a1 = (f32x4){0.f,0.f,0.f,0.f};
        #pragma unroll
        for (int ks = 0; ks < 8; ++ks) {
          half8_t fa0 = *(const half8_t*)&A16[ln15][lq*8 + ks*32];
          half8_t fa1 = *(const half8_t*)&A16[16 + ln15][lq*8 + ks*32];
          a0 = __builtin_amdgcn_mfma_f32_16x16x32_f16(fa0, B0[ks], a0, 0, 0, 0);
          a1 = __builtin_amdgcn_mfma_f32_16x16x32_f16(fa1, B0[ks], a1, 0, 0, 0);
        }
        #pragma unroll
        for (int j = 0; j < 4; ++j) {
          ins3(p1[0][j], p2[0][j], p3[0][j], packsc(fmaf(-2.f, a0[j], e2v), code));
          ins3(p1[1][j], p2[1][j], p3[1][j], packsc(fmaf(-2.f, a1[j], e2v), code));
        }
      }
      if (nt + 2 < 32) {
        const _Float16* bp2 = ebase + (size_t)(nt+2)*16*DD;
        #pragma unroll
        for (int ks = 0; ks < 8; ++ks) B0[ks] = *(const half8_t*)(bp2 + ks*32);
      }
      {
        int code = wave*512 + (nt+1)*16 + ln15;
        float e2v = e2b[code];
        f32x4 a0 = (f32x4){0.f,0.f,0.f,0.f};
        f32x4 a1 = (f32x4){0.f,0.f,0.f,0.f};
        #pragma unroll
        for (int ks = 0; ks < 8; ++ks) {
          half8_t fa0 = *(const half8_t*)&A16[ln15][lq*8 + ks*32];
          half8_t fa1 = *(const half8_t*)&A16[16 + ln15][lq*8 + ks*32];
          a0 = __builtin_amdgcn_mfma_f32_16x16x32_f16(fa0, B1[ks], a0, 0, 0, 0);
          a1 = __builtin_amdgcn_mfma_f32_16x16x32_f16(fa1, B1[ks], a1, 0, 0, 0);
        }
        #pragma unroll
        for (int j = 0; j < 4; ++j) {
          ins3(p1[0][j], p2[0][j], p3[0][j], packsc(fmaf(-2.f, a0[j], e2v), code));
          ins3(p1[1][j], p2[1][j], p3[1][j], packsc(fmaf(-2.f, a1[j], e2v), code));
        }
      }
    }

    // ---- in-wave reduce over the 16 code-columns, then cross-wave ----
    #pragma unroll
    for (int mt = 0; mt < 2; ++mt)
      #pragma unroll
      for (int j = 0; j < 4; ++j) {
        uint32_t v1 = p1[mt][j], v2 = p2[mt][j], v3 = p3[mt][j];
        #pragma unroll
        for (int m = 1; m <= 8; m <<= 1) {
          uint32_t w1 = (uint32_t)__shfl_xor((int)v1, m);
          uint32_t w2 = (uint32_t)__shfl_xor((int)v2, m);
          uint32_t w3 = (uint32_t)__shfl_xor((int)v3, m);
          ins3(v1, v2, v3, w1);
          ins3(v1, v2, v3, w2);
          ins3(v1, v2, v3, w3);
        }
        if (ln15 == 0) {
          int rl = mt*16 + lq*4 + j;
          L1[wave][rl] = v1; L2[wave][rl] = v2; L3[wave][rl] = v3;
        }
      }
    __syncthreads();                            // S2
    if (tid < RPB) {
      uint32_t v1 = L1[0][tid], v2 = L2[0][tid], v3 = L3[0][tid];
      #pragma unroll
      for (int w = 1; w < 4; ++w) {
        ins3(v1, v2, v3, L1[w][tid]);
        ins3(v1, v2, v3, L2[w][tid]);
        ins3(v1, v2, v3, L3[w][tid]);
      }
      int a1 = (int)(v1 & 2047u), a2 = (int)(v2 & 2047u);
      float f1 = unpacksc(v1), f2 = unpacksc(v2), f3 = unpacksc(v3);
      codes_s[tid] = a1;
      int rg = row0 + tid;
      codes_f[((size_t)(rg >> 12)*NBOOKS + ib)*TT + (rg & (TT-1))] = (float)a1;
      if (ib == 0) codes0[rg] = a1;
      if (f3 - f1 < EPS_FULL) {
        flist[atomicAdd(&nfull, 1)] = tid;
      } else if (f2 - f1 < EPS_PAIR) {
        plist[atomicAdd(&npair, 1)] = tid | (a1 << 6) | (a2 << 17);
      }
    }
    __syncthreads();                            // S3

    // ---- full fp64 re-rank (rare: 3rd-best within EPS of best) ----
    int nfl = nfull;
    for (int f = 0; f < nfl; ++f) {
      int row = flist[f];
      double bestv = DBL_MAX; int besti = 0x7fffffff;
      #pragma unroll
      for (int q = 0; q < 8; ++q) {
        int k = q*256 + tid;
        const float* er = Eb + (size_t)k*DD;
        double s = 0.0;
        for (int d = 0; d < DD; d += 4) {
          float4 e = *(const float4*)(er + d);
          double d0 = (double)Z[row][d+0] - (double)e.x; s += d0*d0;
          double d1 = (double)Z[row][d+1] - (double)e.y; s += d1*d1;
          double d2 = (double)Z[row][d+2] - (double)e.z; s += d2*d2;
          double d3 = (double)Z[row][d+3] - (double)e.w; s += d3*d3;
        }
        if (s < bestv || (s == bestv && k < besti)) { bestv = s; besti = k; }
      }
      #pragma unroll
      for (int m = 1; m <= 32; m <<= 1) {
        double ov = __shfl_xor(bestv, m);
        int    oi = __shfl_xor(besti, m);
        if (ov < bestv || (ov == bestv && oi < besti)) { bestv = ov; besti = oi; }
      }
      if (lane == 0) { Rv[wave] = bestv; Ri[wave] = besti; }
      __syncthreads();
      if (tid == 0) {
        double bvv = Rv[0]; int bii = Ri[0];
        #pragma unroll
        for (int w = 1; w < 4; ++w)
          if (Rv[w] < bvv || (Rv[w] == bvv && Ri[w] < bii)) { bvv = Rv[w]; bii = Ri[w]; }
        codes_s[row] = bii;
        int rg = row0 + row;
        codes_f[((size_t)(rg >> 12)*NBOOKS + ib)*TT + (rg & (TT-1))] = (float)bii;
        if (ib == 0) codes0[rg] = bii;
      }
      __syncthreads();
    }

    // ---- pairwise fp64 refine: one wave per flagged row, compares top-2 ----
    {
      int npr = npair;
      for (int f = wave; f < npr; f += 4) {
        int pk = plist[f];
        int row = pk & 63;
        int c1 = (pk >> 6) & 2047, c2 = (pk >> 17) & 2047;
        int cc = (lane < 32) ? c1 : c2;
        const float* er = Eb + (size_t)cc*DD + (lane & 31)*8;
        const float* zr = &Z[row][(lane & 31)*8];
        double s = 0.0;
        #pragma unroll
        for (int d = 0; d < 8; ++d) {
          double df = (double)zr[d] - (double)er[d];
          s += df*df;
        }
        #pragma unroll
        for (int m = 1; m <= 16; m <<= 1) s += __shfl_xor(s, m);
        double so = __shfl_xor(s, 32);
        double d1 = (lane < 32) ? s : so;
        double d2 = (lane < 32) ? so : s;
        int win = (d2 < d1 || (d2 == d1 && c2 < c1)) ? c2 : c1;
        if (lane == 0) {
          codes_s[row] = win;
          int rg = row0 + row;
          codes_f[((size_t)(rg >> 12)*NBOOKS + ib)*TT + (rg & (TT-1))] = (float)win;
          if (ib == 0) codes0[rg] = win;
        }
      }
    }
    __syncthreads();                            // S4: codes_s final

    // ---- f32 residual subtract in LDS (acoustic books only) ----
    if (ib >= 1) {
      int code = codes_s[sr];
      const float* er = Eb + (size_t)code*DD;
      #pragma unroll
      for (int j = 0; j < 8; ++j) {
        int c = sg*4 + j*32;
        float4 e = *(const float4*)(er + c);
        float4 z = *(const float4*)&Z[sr][c];
        z.x -= e.x; z.y -= e.y; z.z -= e.z; z.w -= e.w;
        *(float4*)&Z[sr][c] = z;
      }
    }
    __syncthreads();                            // S5: Z stable for next book
  }

  // ---- aco = xa_initial - xa_final ----
  {
    const float* xp = xa_g + (size_t)(row0 + ldr)*DD + cg*32;
    float*       ap = aco_g + (size_t)(row0 + ldr)*DD + cg*32;
    #pragma unroll
    for (int j = 0; j < 8; ++j) {
      float4 x0 = *(const float4*)(xp + j*4);
      float4 zf = *(const float4*)&Z[ldr][cg*32 + j*4];
      float4 o;
      o.x = x0.x - zf.x; o.y = x0.y - zf.y; o.z = x0.z - zf.z; o.w = x0.w - zf.w;
      *(float4*)(ap + j*4) = o;
    }
  }
}

// ---------------- decode ----------------
__global__ __launch_bounds__(256) void final_kernel(
    const float* __restrict__ Wos, const float* __restrict__ Woa,
    const float* __restrict__ E0, const int* __restrict__ codes0,
    const float* __restrict__ aco, float* __restrict__ out)
{
  __shared__ float wsl[16*68], wal[16*68], sml[16*68], acl[16*68];
  const int tid = threadIdx.x;
  const int t0 = blockIdx.x*64, c0 = blockIdx.y*64, b = blockIdx.z;
  const int u = tid & 63, dq = tid >> 6;
  const int tx = tid & 15, ty = tid >> 4;
  int code = codes0[b*TT + t0 + u];
  const float* smr = E0 + (size_t)code*DD;
  const float* acr = aco + (size_t)(b*TT + t0 + u)*DD;
  const float* wsr = Wos + (size_t)(c0+u)*DD;
  const float* war = Woa + (size_t)(c0+u)*DD;
  float accS[4][4] = {{0}}, accA[4][4] = {{0}};
  for (int dc0 = 0; dc0 < DD; dc0 += 16) {
    __syncthreads();
    float4 v;
    v = *(const float4*)(wsr + dc0 + dq*4);
    wsl[(dq*4+0)*68+u]=v.x; wsl[(dq*4+1)*68+u]=v.y; wsl[(dq*4+2)*68+u]=v.z; wsl[(dq*4+3)*68+u]=v.w;
    v = *(const float4*)(war + dc0 + dq*4);
    wal[(dq*4+0)*68+u]=v.x; wal[(dq*4+1)*68+u]=v.y; wal[(dq*4+2)*68+u]=v.z; wal[(dq*4+3)*68+u]=v.w;
    v = *(const float4*)(smr + dc0 + dq*4);
    sml[(dq*4+0)*68+u]=v.x; sml[(dq*4+1)*68+u]=v.y; sml[(dq*4+2)*68+u]=v.z; sml[(dq*4+3)*68+u]=v.w;
    v = *(const float4*)(acr + dc0 + dq*4);
    acl[(dq*4+0)*68+u]=v.x; acl[(dq*4+1)*68+u]=v.y; acl[(dq*4+2)*68+u]=v.z; acl[(dq*4+3)*68+u]=v.w;
    __syncthreads();
    #pragma unroll
    for (int d = 0; d < 16; ++d) {
      float4 cs = *(const float4*)&wsl[d*68 + tx*4];
      float4 ca = *(const float4*)&wal[d*68 + tx*4];
      float4 ts = *(const float4*)&sml[d*68 + ty*4];
      float4 ta = *(const float4*)&acl[d*68 + ty*4];
      float csf[4]={cs.x,cs.y,cs.z,cs.w}, caf[4]={ca.x,ca.y,ca.z,ca.w};
      float tsf[4]={ts.x,ts.y,ts.z,ts.w}, taf[4]={ta.x,ta.y,ta.z,ta.w};
      #pragma unroll
      for (int i = 0; i < 4; ++i)
        #pragma unroll
        for (int j = 0; j < 4; ++j) {
          accS[i][j] = fmaf(csf[i], tsf[j], accS[i][j]);
          accA[i][j] = fmaf(caf[i], taf[j], accA[i][j]);
        }
    }
  }
  size_t ob = (size_t)b*CC*TT;
  #pragma unroll
  for (int i = 0; i < 4; ++i) {
    float4 r;
    r.x = accS[i][0] + accA[i][0];
    r.y = accS[i][1] + accA[i][1];
    r.z = accS[i][2] + accA[i][2];
    r.w = accS[i][3] + accA[i][3];
    *(float4*)&out[ob + (size_t)(c0 + tx*4 + i)*TT + t0 + ty*4] = r;
  }
}

extern "C" void kernel_launch(void* const* d_in, const int* in_sizes, int n_in,
                              void* d_out, int out_size, void* d_ws, size_t ws_size,
                              hipStream_t stream) {
  const float* x    = (const float*)d_in[0];
  const float* Wins = (const float*)d_in[1];
  const float* Wina = (const float*)d_in[2];
  const float* Wos  = (const float*)d_in[3];
  const float* Woa  = (const float*)d_in[4];
  const float* E    = (const float*)d_in[5];
  float* out = (float*)d_out;
  float* codes_f = out + (size_t)BB*CC*TT;

  // E16 plane lives in the front of d_out (18.9MB; codes_f starts at 33.6MB;
  // out[0:8.4M floats] fully overwritten by final_kernel afterwards).
  _Float16* E16 = (_Float16*)d_out;

  float* xs  = (float*)d_ws;
  float* xa  = xs + (size_t)MM*DD;
  float* aco = xa + (size_t)MM*DD;
  float* e2  = aco + (size_t)MM*DD;
  int* codes_i = (int*)(e2 + 18*KK);

  proj_kernel<<<dim3(TT/64, DD/64, BB), 256, 0, stream>>>(x, Wins, Wina, xs, xa);
  e2_kernel<<<(18*KK*64)/256, 256, 0, stream>>>(E, e2);
  cvt_e16_kernel<<<(18*KK*DD)/8/256, 256, 0, stream>>>(E, E16);

  fused_encode_kernel<<<MM/RPB, 256, 0, stream>>>(xs, xa, E, E16, e2,
                                                  codes_i, codes_f, aco);

  final_kernel<<<dim3(TT/64, CC/64, BB), 256, 0, stream>>>(Wos, Woa, E, codes_i, aco, out);
}